// Round 7
// baseline (376.798 us; speedup 1.0000x reference)
//
#include <hip/hip_runtime.h>
#include <stdint.h>
#include <type_traits>

// Problem constants
#define BB  4
#define SS  2048
#define DD  1024
#define HH  16
#define HDD 64

typedef __attribute__((ext_vector_type(8)))  short s16x8;   // 8 bf16 (4 VGPRs)
typedef __attribute__((ext_vector_type(4)))  float f32x4;   // MFMA C/D 16x16
typedef __attribute__((ext_vector_type(16))) float f32x16;  // MFMA C/D 32x32

__device__ inline short f2bf(float f) {
    union { float f; unsigned int u; } v; v.f = f;
    unsigned int r = (v.u + 0x7fffu + ((v.u >> 16) & 1u)) >> 16; // RNE
    return (short)r;
}
// pack two f32 -> bf16x2 with +0x8000 round (1 v_perm + 2 v_add)
__device__ inline unsigned int permpack(float a, float b) {
    union { float f; unsigned int u; } x, y; x.f = a; y.f = b;
    return __builtin_amdgcn_perm(y.u + 0x8000u, x.u + 0x8000u, 0x07060302u);
}

#define GLL(gp, lp) __builtin_amdgcn_global_load_lds( \
    (const __attribute__((address_space(1))) void*)(gp), \
    (__attribute__((address_space(3))) void*)(lp), 16, 0, 0)

// ---------------- fp32 -> bf16 cast (n % 8 == 0) ----------------
__global__ void cvt_kernel(const float* __restrict__ src, short* __restrict__ dst, int n) {
    int i = (blockIdx.x * 256 + threadIdx.x) * 8;
    if (i >= n) return;
    const float4* s = (const float4*)(src + i);
    float4 a = s[0], b = s[1];
    s16x8 o;
    o[0]=f2bf(a.x); o[1]=f2bf(a.y); o[2]=f2bf(a.z); o[3]=f2bf(a.w);
    o[4]=f2bf(b.x); o[5]=f2bf(b.y); o[6]=f2bf(b.z); o[7]=f2bf(b.w);
    *(s16x8*)(dst + i) = o;
}

// ---------------- GEMM C = A @ B^T + bias (m97 structure) ----------------
// NOTE: byte-identical to the R4/R6 version (healthy). Do not touch.
template<int EPI>
__global__ __launch_bounds__(256)
void gemm_bt(const short* __restrict__ A, const short* __restrict__ Bw,
             const float* __restrict__ bias, float* __restrict__ Cf,
             short* __restrict__ Qo, short* __restrict__ Ko, short* __restrict__ Vo,
             int M, int N, int K)
{
    __shared__ short lsA[128 * 32];
    __shared__ short lsB[128 * 32];
    const int tid  = threadIdx.x;
    const int w    = tid >> 6, lane = tid & 63;
    const int quad = lane >> 4, l15 = lane & 15;
    const int m0 = blockIdx.x * 128, n0 = blockIdx.y * 128;
    const int mw = (w & 1) * 64, nw = (w >> 1) * 64;

    f32x4 acc[4][4] = {};

    const int srow = w * 32 + (lane >> 2);
    const int scol = (lane & 3) * 8;
    const short* pA = A + (size_t)(m0 + srow) * K + scol;
    const short* pB = Bw + (size_t)(n0 + srow) * K + scol;
    short* lAbase0 = &lsA[(w * 32) * 32];
    short* lAbase1 = &lsA[(w * 32 + 16) * 32];
    short* lBbase0 = &lsB[(w * 32) * 32];
    short* lBbase1 = &lsB[(w * 32 + 16) * 32];

    for (int kk = 0; kk < K; kk += 32) {
        __syncthreads();
        GLL(pA + kk,            lAbase0);
        GLL(pA + kk + 16 * K,   lAbase1);
        GLL(pB + kk,            lBbase0);
        GLL(pB + kk + 16 * K,   lBbase1);
        asm volatile("s_waitcnt vmcnt(0)" ::: "memory");
        __syncthreads();

        s16x8 af[4], bfr[4];
        for (int t = 0; t < 4; ++t) {
            af[t]  = *(const s16x8*)&lsA[(mw + t * 16 + l15) * 32 + quad * 8];
            bfr[t] = *(const s16x8*)&lsB[(nw + t * 16 + l15) * 32 + quad * 8];
        }
        for (int i = 0; i < 4; ++i)
            for (int j = 0; j < 4; ++j)
                acc[i][j] = __builtin_amdgcn_mfma_f32_16x16x32_bf16(af[i], bfr[j], acc[i][j], 0, 0, 0);
    }

    if (EPI == 0) {
        for (int i = 0; i < 4; ++i) {
            int row = m0 + mw + i * 16 + quad * 4;
            for (int j = 0; j < 4; ++j) {
                int col = n0 + nw + j * 16 + l15;
                float bv = bias[col];
                for (int r = 0; r < 4; ++r)
                    Cf[(size_t)(row + r) * N + col] = acc[i][j][r] + bv;
            }
        }
    } else {
        for (int i = 0; i < 4; ++i) {
            int row = m0 + mw + i * 16 + quad * 4;
            for (int j = 0; j < 4; ++j) {
                int col = n0 + nw + j * 16 + l15;
                float bv = bias[col];
                int sel = col >> 10, h = (col >> 6) & 15, hd = col & 63;
                for (int r = 0; r < 4; ++r) {
                    int rr = row + r;
                    int b = rr >> 11, s = rr & 2047;
                    short val = f2bf(acc[i][j][r] + bv);
                    if (sel == 0)      Qo[(((size_t)b * HH + h) * SS + s) * HDD + hd] = val;
                    else if (sel == 1) Ko[(((size_t)b * HH + h) * SS + s) * HDD + hd] = val;
                    else               Vo[(((size_t)b * HH + h) * HDD + hd) * SS + s] = val;
                }
            }
        }
    }
}

// ---------------- causal flash attention, fine-grained blocks ----------------
// Q,K: (b,h,s,hd) bf16; V: (b,h,hd,s) bf16; O: (b,s,h*64+hd) bf16.
// grid (64, B*H) = 4096 blocks (4x resident capacity -> HW refill as light
// blocks finish), heavy-first (qs = 63-bx). Block = 32 q-rows, 4 waves:
// wave w takes key-half (w&1) and hd-half (w>>1) of each 64-key tile; QK is
// duplicated across hd-halves (MFMA is cheap); O partials combined across
// key-halves once at the end via LDS. K/V dbuf + GLL prefetch (R6 pipeline).
__global__ __launch_bounds__(256, 4)
void attn_kernel(const short* __restrict__ Q, const short* __restrict__ Kb,
                 const short* __restrict__ Vb, const int* __restrict__ mask,
                 short* __restrict__ O)
{
    __shared__ short lsK[2][64 * 64];   // chunk p=key*8+(s^(key&7)) holds K[kv0+key][s'*8..]
    __shared__ short lsV[2][64 * 64];   // chunk p=hd*8+(s^(hd&7))  holds V^T[hd][kv0+s'*8..]
    __shared__ float lsM[2][64];        // additive key mask

    const int tid = threadIdx.x;
    const int w   = tid >> 6, lane = tid & 63;
    const int h   = lane >> 5, q = lane & 31;     // intra-fragment half, q-column
    const int kh  = w & 1, hdh = w >> 1;          // wave's key-half, hd-half
    const int bx = blockIdx.x, bh = blockIdx.y;
    const int qs = 63 - bx;                       // heavy-first dispatch
    const int b = bh >> 4;
    const size_t baseQK = (size_t)bh * SS * HDD;
    const size_t baseV  = (size_t)bh * HDD * SS;
    const int s_row = qs * 32 + q;                // this lane's q row
    const int T = (qs >> 1) + 1;                  // 64-key tiles (only last crosses diag)
    const float SC = 0.18033688f;                 // (1/8) * log2(e)

    // Q fragments (B-frag: n=q, k=hd=kb*16+h*8+j)
    s16x8 bq[4];
    for (int kb = 0; kb < 4; ++kb)
        bq[kb] = *(const s16x8*)(Q + baseQK + (size_t)s_row * HDD + kb * 16 + h * 8);

    // staging addresses: 2 GLL rounds each for K and V (512 chunks of 8 el)
    const short* gK[2]; const short* gV[2]; int lofs[2];
    for (int i = 0; i < 2; ++i) {
        const int p = w * 128 + i * 64 + lane;
        const int kr = p >> 3, sc = p & 7;
        gK[i] = Kb + baseQK + (size_t)kr * HDD + ((sc ^ (kr & 7)) * 8);
        gV[i] = Vb + baseV + (size_t)kr * SS + ((sc ^ (kr & 7)) * 8);
        lofs[i] = (w * 128 + i * 64) * 8;         // wave-uniform LDS chunk base (shorts)
    }
    const int* mbase = mask + b * SS;

    float lsum = 0.f;
    f32x16 oa = {};   // O^T partial: rows hd = hdh*32+8g+4h+r, col q; this wave's key-half

    // ---- preamble: stage tile 0 into buf 0 ----
    for (int i = 0; i < 2; ++i) {
        GLL(gK[i], &lsK[0][lofs[i]]);
        GLL(gV[i], &lsV[0][lofs[i]]);
    }
    if (tid < 16) {
        int4 mv = *(const int4*)(mbase + tid * 4);
        float4 f;
        f.x = mv.x ? 0.f : -1e30f; f.y = mv.y ? 0.f : -1e30f;
        f.z = mv.z ? 0.f : -1e30f; f.w = mv.w ? 0.f : -1e30f;
        *(float4*)&lsM[0][tid * 4] = f;
    }
    __syncthreads();

    auto step = [&](int kt, auto CC) {
        constexpr bool CAUS = decltype(CC)::value;
        const int cur = kt & 1, nxt = cur ^ 1;
        const int kv0 = kt * 64;

        // prefetch tile kt+1 into buf[nxt]
        int4 mv;
        const bool pf = (kt + 1 < T);
        if (pf) {
            const size_t okK = (size_t)(kv0 + 64) * HDD;
            const int   okV = kv0 + 64;
            for (int i = 0; i < 2; ++i) {
                GLL(gK[i] + okK, &lsK[nxt][lofs[i]]);
                GLL(gV[i] + okV, &lsV[nxt][lofs[i]]);
            }
            if (tid < 16) mv = *(const int4*)(mbase + kv0 + 64 + tid * 4);
        }

        // ---- compute this wave's 32-key half from buf[cur] ----
        // S^T (32 keys x 32 q): A = K frag, m = key = kh*32 + q
        f32x16 sa = {};
        const int keyl = kh * 32 + q;
        for (int kb = 0; kb < 4; ++kb) {
            const int cc = (kb * 2 + h) ^ (keyl & 7);
            s16x8 ak = *(const s16x8*)&lsK[cur][(keyl * 8 + cc) * 8];
            sa = __builtin_amdgcn_mfma_f32_32x32x16_bf16(ak, bq[kb], sa, 0, 0, 0);
        }
        // softmax (fixed-offset, log2 domain)
        unsigned int pk2[4][2];
        for (int g = 0; g < 4; ++g) {
            float4 mq = *(const float4*)&lsM[cur][kh * 32 + 8 * g + 4 * h];
            float pv[4];
            for (int r = 0; r < 4; ++r) {
                float v = sa[g * 4 + r] * SC + ((const float*)&mq)[r];
                if (CAUS) {
                    int keyg = kv0 + kh * 32 + 8 * g + 4 * h + r;
                    if (keyg > s_row) v = -1e30f;
                }
                float p = __builtin_amdgcn_exp2f(v);
                pv[r] = p;
                lsum += p;
            }
            pk2[g][0] = permpack(pv[0], pv[1]);
            pk2[g][1] = permpack(pv[2], pv[3]);
        }
        // O^T += V^T P^T over this wave's 32 keys (2 k-frags of 16)
        for (int kb2 = 0; kb2 < 2; ++kb2) {
            const int g_own = 2 * kb2 + h;
            unsigned int s0 = h ? pk2[2 * kb2][0] : pk2[2 * kb2 + 1][0];
            unsigned int s1 = h ? pk2[2 * kb2][1] : pk2[2 * kb2 + 1][1];
            unsigned int r0 = (unsigned int)__shfl_xor((int)s0, 32);
            unsigned int r1 = (unsigned int)__shfl_xor((int)s1, 32);
            union { s16x8 v; unsigned int d[4]; } bp;
            if (h == 0) { bp.d[0] = pk2[g_own][0]; bp.d[1] = pk2[g_own][1]; bp.d[2] = r0; bp.d[3] = r1; }
            else        { bp.d[0] = r0; bp.d[1] = r1; bp.d[2] = pk2[g_own][0]; bp.d[3] = pk2[g_own][1]; }
            const int hd = hdh * 32 + q;                      // A m index
            const int cc = (kh * 4 + kb2 * 2 + h) ^ (hd & 7); // key chunk, swizzled
            s16x8 av = *(const s16x8*)&lsV[cur][(hd * 8 + cc) * 8];
            oa = __builtin_amdgcn_mfma_f32_32x32x16_bf16(av, bp.v, oa, 0, 0, 0);
        }

        if (pf && tid < 16) {
            float4 f;
            f.x = mv.x ? 0.f : -1e30f; f.y = mv.y ? 0.f : -1e30f;
            f.z = mv.z ? 0.f : -1e30f; f.w = mv.w ? 0.f : -1e30f;
            *(float4*)&lsM[nxt][tid * 4] = f;
        }
        __syncthreads();
    };

    for (int kt = 0; kt < T - 1; ++kt) step(kt, std::false_type{});
    step(T - 1, std::true_type{});

    // ---- combine key-halves (waves kh=1 -> kh=0) via LDS, then store ----
    float ls2 = lsum + __shfl_xor(lsum, 32);      // reduce over h
    float* cmb = (float*)&lsK[0][0];              // 16 KB, dead now
    float* cls = (float*)&lsV[0][0];
    if (kh == 1) {
        *(f32x16*)(cmb + hdh * 1024 + lane * 16) = oa;
        cls[hdh * 64 + lane] = ls2;
    }
    __syncthreads();
    if (kh == 0) {
        f32x16 po = *(const f32x16*)(cmb + hdh * 1024 + lane * 16);
        float lt = ls2 + cls[hdh * 64 + lane];
        float inv = 1.0f / lt;
        const int hcol = (bh & 15) * HDD;
        const size_t obase = ((size_t)b * SS + s_row) * DD + hcol;
        for (int g = 0; g < 4; ++g) {
            const int hd0 = hdh * 32 + 8 * g + 4 * h;
            uint2 st;
            st.x = permpack((oa[g * 4 + 0] + po[g * 4 + 0]) * inv,
                            (oa[g * 4 + 1] + po[g * 4 + 1]) * inv);
            st.y = permpack((oa[g * 4 + 2] + po[g * 4 + 2]) * inv,
                            (oa[g * 4 + 3] + po[g * 4 + 3]) * inv);
            *(uint2*)&O[obase + hd0] = st;
        }
    }
}

// ---------------- launch ----------------
extern "C" void kernel_launch(void* const* d_in, const int* in_sizes, int n_in,
                              void* d_out, int out_size, void* d_ws, size_t ws_size,
                              hipStream_t stream) {
    const float* x     = (const float*)d_in[0];
    const int*   mask  = (const int*)d_in[1];
    const float* qkv_w = (const float*)d_in[2];
    const float* qkv_b = (const float*)d_in[3];
    const float* out_w = (const float*)d_in[4];
    const float* out_b = (const float*)d_in[5];
    float* out = (float*)d_out;

    const size_t M1 = (size_t)BB * SS;       // 8192
    short* ws  = (short*)d_ws;
    short* xb  = ws;
    short* qwb = xb  + M1 * DD;
    short* owb = qwb + (size_t)3 * DD * DD;
    short* Qb  = owb + (size_t)DD * DD;
    short* Kb  = Qb  + M1 * DD;
    short* Vb  = Kb  + M1 * DD;
    short* Ob  = Vb  + M1 * DD;

    cvt_kernel<<<(int)(M1 * DD / 8 / 256), 256, 0, stream>>>(x, xb, (int)(M1 * DD));
    cvt_kernel<<<3 * DD * DD / 8 / 256, 256, 0, stream>>>(qkv_w, qwb, 3 * DD * DD);
    cvt_kernel<<<DD * DD / 8 / 256, 256, 0, stream>>>(out_w, owb, DD * DD);

    gemm_bt<1><<<dim3(64, 24), 256, 0, stream>>>(xb, qwb, qkv_b, nullptr,
                                                 Qb, Kb, Vb, 8192, 3072, 1024);
    attn_kernel<<<dim3(64, BB * HH), 256, 0, stream>>>(Qb, Kb, Vb, mask, Ob);
    gemm_bt<0><<<dim3(64, 8), 256, 0, stream>>>(Ob, owb, out_b, out,
                                                nullptr, nullptr, nullptr, 8192, 1024, 1024);
}